// Round 5
// baseline (68.897 us; speedup 1.0000x reference)
//
#include <hip/hip_runtime.h>
#include <cfloat>
#include <cstddef>

// Problem constants (fixed by setup_inputs): B=32, n=512, H=768, k=5
#define NB 32
#define NN 512
#define NH 768
#define H4 (NH / 4)        // 192 float4 per encI row
#define ROWS (NB * NN)     // 16384
#define MAXK 8
#define CHUNKS 32          // row-sum partial chunks per batch
#define RPC (NN / CHUNKS)  // 16 rows per chunk
#define INF_C 3000.0f
#define SELF_D 9000000.0f  // INF*INF self-distance

typedef float f32x4 __attribute__((ext_vector_type(4)));

__device__ __forceinline__ void nt_store4(float4* p, float4 v) {
  f32x4 t; t.x = v.x; t.y = v.y; t.z = v.z; t.w = v.w;
  __builtin_nontemporal_store(t, (f32x4*)p);
}

// ---------------------------------------------------------------------------
// 64-lane sum: 4 DPP steps (xor1, xor2, half-row mirror, row mirror) on the
// VALU pipe, then ds_swizzle xor16 and shfl xor32. Validated in round 4.
// ---------------------------------------------------------------------------
template <int CTRL>
__device__ __forceinline__ float dpp_add(float x) {
  int yi = __builtin_amdgcn_update_dpp(0, __float_as_int(x), CTRL, 0xF, 0xF, true);
  return x + __int_as_float(yi);
}
__device__ __forceinline__ float wave_sum64(float x) {
  x = dpp_add<0xB1>(x);
  x = dpp_add<0x4E>(x);
  x = dpp_add<0x141>(x);
  x = dpp_add<0x140>(x);
  x += __int_as_float(__builtin_amdgcn_ds_swizzle(__float_as_int(x), 0x401F));
  x += __shfl_xor(x, 32, 64);
  return x;
}

// ---------------------------------------------------------------------------
// Kernel 1 (prep): 1024 blocks x 192 threads. Block (b, chunk) sums 16 rows
// into a partial AND copies those rows into the first half of the output.
// part layout: [(b*32 + chunk)][col]  (float4)
// ---------------------------------------------------------------------------
__global__ __launch_bounds__(192) void prep_kernel(const float4* __restrict__ e4,
                                                   float4* __restrict__ out4,
                                                   float4* __restrict__ part) {
  int t = threadIdx.x;                        // col 0..191
  int bid = blockIdx.x;                       // 0..1023
  int b = bid >> 5, chunk = bid & 31;
  int row0 = b * NN + chunk * RPC;
  const float4* p = e4 + (size_t)row0 * H4 + t;
  float4* o = out4 + (size_t)row0 * (2 * H4) + t;
  float ax = 0.f, ay = 0.f, az = 0.f, aw = 0.f;
#pragma unroll 4
  for (int r = 0; r < RPC; ++r) {
    float4 v = p[(size_t)r * H4];
    ax += v.x; ay += v.y; az += v.z; aw += v.w;
    nt_store4(o + (size_t)r * (2 * H4), v);
  }
  part[(size_t)bid * H4 + t] = make_float4(ax, ay, az, aw);
}

// ---------------------------------------------------------------------------
// Fused body (topk + gather + dots + sparse softmax + context-half store).
// context = c0*S + sum_valid (c_s - c0) * e_j,
//   c_s = exp(sim_s - M)/Z, c0 = exp(-M)/Z,
//   Z = (512 - m)*exp(-M) + sum_valid exp(sim_s - M), M = max(0, max valid sim)
// GUARD=false requires k == K exactly. ctr/mask/S come from LDS.
// ---------------------------------------------------------------------------
template <int K, bool GUARD>
__device__ __forceinline__ void fuse_body(const float2* __restrict__ ctr_s,
                                          const int* __restrict__ mask_s,
                                          const float4* __restrict__ S_s,
                                          const float4* __restrict__ e4,
                                          float4* __restrict__ out4,
                                          const float4 (&ei)[3],
                                          int row, int b, int i, int lane, int k) {
  // --- top-k nearest from LDS centers (ties -> smaller index, = jax.lax.top_k)
  float2 ci = ctr_s[i];
  float dv[8];
#pragma unroll
  for (int c = 0; c < 8; ++c) {
    int j = c * 64 + lane;
    float2 cj = ctr_s[j];
    float dx = __fadd_rn(ci.x, -cj.x);
    float dy = __fadd_rn(ci.y, -cj.y);
    float d = __fsqrt_rn(__fadd_rn(__fmul_rn(dx, dx), __fmul_rn(dy, dy)));
    dv[c] = (j == i) ? SELF_D : d;
  }
  int sel[K];
#pragma unroll
  for (int s = 0; s < K; ++s) {
    sel[s] = 0;
    if (!GUARD || s < k) {                    // wave-uniform
      float bv = FLT_MAX;
      int bj = 1 << 30;
#pragma unroll
      for (int c = 0; c < 8; ++c) {
        int j = c * 64 + lane;
        if (dv[c] < bv) { bv = dv[c]; bj = j; }
      }
#pragma unroll
      for (int off = 1; off < 64; off <<= 1) {
        float ov = __shfl_xor(bv, off, 64);
        int oj = __shfl_xor(bj, off, 64);
        if (ov < bv || (ov == bv && oj < bj)) { bv = ov; bj = oj; }
      }
      sel[s] = bj;
#pragma unroll
      for (int c = 0; c < 8; ++c)
        if (c * 64 + lane == bj) dv[c] = FLT_MAX;
    }
  }

  // --- gathers (all independent, issued together) + validity from LDS mask
  float4 ej[K][3];
  int valid[K];
#pragma unroll
  for (int s = 0; s < K; ++s) {
    const float4* ero = e4 + (size_t)(b * NN + sel[s]) * H4;
#pragma unroll
    for (int q = 0; q < 3; ++q) ej[s][q] = ero[q * 64 + lane];
    valid[s] = (!GUARD || s < k) ? mask_s[sel[s]] : 0;
  }

  // --- dot products (K-way ILP, DPP-assisted wave sum)
  float d[K];
#pragma unroll
  for (int s = 0; s < K; ++s) {
    float p = 0.f;
#pragma unroll
    for (int q = 0; q < 3; ++q) {
      p = fmaf(ei[q].x, ej[s][q].x, p);
      p = fmaf(ei[q].y, ej[s][q].y, p);
      p = fmaf(ei[q].z, ej[s][q].z, p);
      p = fmaf(ei[q].w, ej[s][q].w, p);
    }
    d[s] = wave_sum64(p);
  }

  // --- sparse softmax closed form
  float M = 0.f;
  int m = 0;
#pragma unroll
  for (int s = 0; s < K; ++s)
    if (valid[s]) { ++m; M = fmaxf(M, d[s]); }
  float e0 = expf(-M);
  float Z = (float)(NN - m) * e0;
  float es[K];
#pragma unroll
  for (int s = 0; s < K; ++s) {
    es[s] = valid[s] ? expf(d[s] - M) : 0.f;
    Z += es[s];
  }
  float invZ = 1.0f / Z;
  float c0 = e0 * invZ;

  // --- context accumulation (S from LDS)
  float4 ctx[3];
#pragma unroll
  for (int q = 0; q < 3; ++q) {
    float4 Sv = S_s[q * 64 + lane];
    ctx[q].x = c0 * Sv.x; ctx[q].y = c0 * Sv.y;
    ctx[q].z = c0 * Sv.z; ctx[q].w = c0 * Sv.w;
  }
#pragma unroll
  for (int s = 0; s < K; ++s) {
    if (valid[s]) {                            // wave-uniform
      float cs = es[s] * invZ - c0;
#pragma unroll
      for (int q = 0; q < 3; ++q) {
        ctx[q].x = fmaf(cs, ej[s][q].x, ctx[q].x);
        ctx[q].y = fmaf(cs, ej[s][q].y, ctx[q].y);
        ctx[q].z = fmaf(cs, ej[s][q].z, ctx[q].z);
        ctx[q].w = fmaf(cs, ej[s][q].w, ctx[q].w);
      }
    }
  }

  // --- store context half only (first half written by prep)
  size_t ob = (size_t)row * (2 * H4) + H4;
#pragma unroll
  for (int q = 0; q < 3; ++q) nt_store4(out4 + ob + q * 64 + lane, ctx[q]);
}

// ---------------------------------------------------------------------------
// Kernel 2 (fuse): 4096 blocks x 256 threads; block = 4 rows of one batch.
// Stage A: centers+mask -> LDS (from spatials), partial-reduce S -> LDS,
//          own-row ei loads issued first. Stage B: per-wave fuse_body.
// Chunked XCD swizzle: each XCD owns 4 consecutive batches (L2 locality).
// ---------------------------------------------------------------------------
__global__ __launch_bounds__(256) void fuse_kernel(const float* __restrict__ sp,
                                                   const int* __restrict__ mask,
                                                   const float4* __restrict__ e4,
                                                   const float4* __restrict__ part,
                                                   const int* __restrict__ kptr,
                                                   float4* __restrict__ out4) {
  __shared__ float2 ctr_s[NN];   // 4 KB
  __shared__ int mask_s[NN];     // 2 KB
  __shared__ float4 S_s[H4];     // 3 KB
  int bid = blockIdx.x;
  int swz = (bid & 7) * (4096 / 8) + (bid >> 3);  // bijective: 4096 % 8 == 0
  int b = swz >> 7;                               // 128 blocks per batch
  int i = (swz & 127) * 4 + (threadIdx.x >> 6);   // row within batch
  int lane = threadIdx.x & 63;
  int row = b * NN + i;

  // issue own-row loads first (L3-hot; drain under the LDS staging below)
  const float4* erow = e4 + (size_t)row * H4;
  float4 ei[3];
#pragma unroll
  for (int q = 0; q < 3; ++q) ei[q] = erow[q * 64 + lane];

  // stage centers + mask (2 rows per thread); identical math to reference
#pragma unroll
  for (int r = threadIdx.x; r < NN; r += 256) {
    int mv = mask[b * NN + r];
    mask_s[r] = mv;
    const float* s = sp + (size_t)(b * NN + r) * 6;
    float cx = __fmul_rn(__fadd_rn(s[0], s[2]), 0.5f);
    float cy = __fmul_rn(__fadd_rn(s[1], s[3]), 0.5f);
    if (mv == 0) { cx = __fadd_rn(cx, INF_C); cy = __fadd_rn(cy, INF_C); }
    ctr_s[r] = make_float2(cx, cy);
  }
  // block-level reduce of the 32 chunk partials (cols over threads 0..191)
  if (threadIdx.x < H4) {
    float ax = 0.f, ay = 0.f, az = 0.f, aw = 0.f;
#pragma unroll
    for (int c = 0; c < CHUNKS; ++c) {
      float4 v = part[(size_t)(b * CHUNKS + c) * H4 + threadIdx.x];
      ax += v.x; ay += v.y; az += v.z; aw += v.w;
    }
    S_s[threadIdx.x] = make_float4(ax, ay, az, aw);
  }
  __syncthreads();

  int k = *kptr;
  if (k == 5) {
    fuse_body<5, false>(ctr_s, mask_s, S_s, e4, out4, ei, row, b, i, lane, 5);
  } else {
    if (k > MAXK) k = MAXK;
    if (k < 0) k = 0;
    fuse_body<MAXK, true>(ctr_s, mask_s, S_s, e4, out4, ei, row, b, i, lane, k);
  }
}

// ---------------------------------------------------------------------------
extern "C" void kernel_launch(void* const* d_in, const int* in_sizes, int n_in,
                              void* d_out, int out_size, void* d_ws, size_t ws_size,
                              hipStream_t stream) {
  const float* encI = (const float*)d_in[0];
  const int* RoI_mask = (const int*)d_in[1];
  const float* spatials = (const float*)d_in[2];
  const int* kptr = (const int*)d_in[3];

  // ws: rowsum partials only (NB*CHUNKS*H4 float4 = 3 MB; ws proven >= 3.1 MB)
  float4* part = (float4*)d_ws;

  prep_kernel<<<NB * CHUNKS, 192, 0, stream>>>((const float4*)encI, (float4*)d_out, part);
  fuse_kernel<<<ROWS / 4, 256, 0, stream>>>(spatials, RoI_mask, (const float4*)encI, part,
                                            kptr, (float4*)d_out);
  (void)in_sizes; (void)n_in; (void)out_size; (void)ws_size;
}

// Round 6
// 49.688 us; speedup vs baseline: 1.3866x; 1.3866x over previous
//
#include <hip/hip_runtime.h>
#include <cfloat>
#include <cstddef>

// Problem constants (fixed by setup_inputs): B=32, n=512, H=768, k=5
#define NB 32
#define NN 512
#define NH 768
#define H4 (NH / 4)        // 192 float4 per encI row
#define ROWS (NB * NN)     // 16384
#define MAXK 8
#define CHUNKS 32          // row-sum partial chunks per batch
#define RPC (NN / CHUNKS)  // 16 rows per chunk
#define INF_C 3000.0f
#define SELF_D 9000000.0f  // INF*INF self-distance

typedef float f32x4 __attribute__((ext_vector_type(4)));

__device__ __forceinline__ void nt_store4(float4* p, float4 v) {
  f32x4 t; t.x = v.x; t.y = v.y; t.z = v.z; t.w = v.w;
  __builtin_nontemporal_store(t, (f32x4*)p);
}

// ---------------------------------------------------------------------------
// DPP cross-lane moves (VALU pipe, ~5 cy vs ~40 cy for ds_bpermute shuffles).
// Ctrl codes validated bitwise in round 4 (wave_sum64 matched reference):
//   0xB1 = quad_perm [1,0,3,2]  -> xor1
//   0x4E = quad_perm [2,3,0,1]  -> xor2
//   0x141 = row_half_mirror     -> xor7
//   0x140 = row_mirror          -> xor15
// xor-closure of {1,2,7,15,16,32} = all 64 lanes.
// ---------------------------------------------------------------------------
template <int CTRL>
__device__ __forceinline__ int dpp_i(int x) {
  return __builtin_amdgcn_update_dpp(0, x, CTRL, 0xF, 0xF, true);
}
template <int CTRL>
__device__ __forceinline__ float dpp_f(float x) {
  return __int_as_float(dpp_i<CTRL>(__float_as_int(x)));
}

__device__ __forceinline__ float wave_sum64(float x) {
  x += dpp_f<0xB1>(x);
  x += dpp_f<0x4E>(x);
  x += dpp_f<0x141>(x);
  x += dpp_f<0x140>(x);
  x += __int_as_float(__builtin_amdgcn_ds_swizzle(__float_as_int(x), 0x401F));
  x += __shfl_xor(x, 32, 64);
  return x;
}

// lexicographic argmin step: (bv,bj) <- min((bv,bj), (ov,oj))
#define ARGMIN_COMBINE(ov, oj)                                   \
  do {                                                           \
    float _ov = (ov); int _oj = (oj);                            \
    if (_ov < bv || (_ov == bv && _oj < bj)) { bv = _ov; bj = _oj; } \
  } while (0)

// ---------------------------------------------------------------------------
// Kernel 1: blocks [0,768): row-sum partials (32 chunks x 16 rows per batch)
//           blocks [768,832): adjusted box centers
// ---------------------------------------------------------------------------
__global__ __launch_bounds__(256) void prep_kernel(const float* __restrict__ sp,
                                                   const int* __restrict__ mask,
                                                   const float4* __restrict__ e4,
                                                   float2* __restrict__ ctr,
                                                   float4* __restrict__ part) {
  int bid = blockIdx.x;
  if (bid < 768) {
    int t = bid * 256 + threadIdx.x;          // [0, NB*CHUNKS*H4)
    int h4 = t % H4;
    int bc = t / H4;
    int b = bc >> 5, chunk = bc & 31;
    const float4* p = e4 + ((size_t)(b * NN + chunk * RPC)) * H4 + h4;
    float ax = 0.f, ay = 0.f, az = 0.f, aw = 0.f;
#pragma unroll
    for (int r = 0; r < RPC; ++r) {
      float4 v = p[(size_t)r * H4];
      ax += v.x; ay += v.y; az += v.z; aw += v.w;
    }
    part[t] = make_float4(ax, ay, az, aw);
  } else {
    int t = (bid - 768) * 256 + threadIdx.x;  // [0, ROWS)
    const float* s = sp + (size_t)t * 6;
    float cx = __fmul_rn(__fadd_rn(s[0], s[2]), 0.5f);
    float cy = __fmul_rn(__fadd_rn(s[1], s[3]), 0.5f);
    if (mask[t] == 0) { cx = __fadd_rn(cx, INF_C); cy = __fadd_rn(cy, INF_C); }
    ctr[t] = make_float2(cx, cy);
  }
}

// ---------------------------------------------------------------------------
// Kernel 2: reduce 32 chunk-partials -> S[b][h4]  (24 blocks, ~1-2 us)
// ---------------------------------------------------------------------------
__global__ __launch_bounds__(256) void rowsum_reduce_kernel(const float4* __restrict__ part,
                                                            float4* __restrict__ S4) {
  int t = blockIdx.x * 256 + threadIdx.x;     // [0, NB*H4)
  int h4 = t % H4;
  int b = t / H4;
  float ax = 0.f, ay = 0.f, az = 0.f, aw = 0.f;
#pragma unroll
  for (int c = 0; c < CHUNKS; ++c) {
    float4 v = part[(size_t)(b * CHUNKS + c) * H4 + h4];
    ax += v.x; ay += v.y; az += v.z; aw += v.w;
  }
  S4[t] = make_float4(ax, ay, az, aw);
}

// ---------------------------------------------------------------------------
// Fused body: topk (DPP butterfly) + gather + dots + sparse softmax + context.
// context = c0*S + sum_valid (c_s - c0) * e_j,
//   c_s = exp(sim_s - M)/Z, c0 = exp(-M)/Z,
//   Z = (512 - m)*exp(-M) + sum_valid exp(sim_s - M), M = max(0, max valid sim)
// GUARD=false requires k == K exactly.
// ---------------------------------------------------------------------------
template <int K, bool GUARD>
__device__ __forceinline__ void fuse_body(const float2* __restrict__ ctr,
                                          const int* __restrict__ mask,
                                          const float4* __restrict__ S4,
                                          const float4* __restrict__ e4,
                                          float4* __restrict__ out4,
                                          int row, int b, int i, int lane, int k) {
  // issue own-row loads FIRST so their latency hides under topk compute
  const float4* erow = e4 + (size_t)row * H4;
  float4 ei[3];
#pragma unroll
  for (int q = 0; q < 3; ++q) ei[q] = erow[q * 64 + lane];

  // --- top-k nearest (ties -> smaller index, = jax.lax.top_k order) ---
  float2 ci = ctr[b * NN + i];
  float dv[8];
#pragma unroll
  for (int c = 0; c < 8; ++c) {
    int j = c * 64 + lane;
    float2 cj = ctr[b * NN + j];
    float dx = __fadd_rn(ci.x, -cj.x);
    float dy = __fadd_rn(ci.y, -cj.y);
    float d = __fsqrt_rn(__fadd_rn(__fmul_rn(dx, dx), __fmul_rn(dy, dy)));
    dv[c] = (j == i) ? SELF_D : d;
  }
  int sel[K];
#pragma unroll
  for (int s = 0; s < K; ++s) {
    sel[s] = 0;
    if (!GUARD || s < k) {                    // wave-uniform
      float bv = FLT_MAX;
      int bj = 1 << 30;
#pragma unroll
      for (int c = 0; c < 8; ++c) {
        int j = c * 64 + lane;
        if (dv[c] < bv) { bv = dv[c]; bj = j; }
      }
      // butterfly argmin over xor-generators {1,2,7,15,16,32}
      ARGMIN_COMBINE(dpp_f<0xB1>(bv), dpp_i<0xB1>(bj));
      ARGMIN_COMBINE(dpp_f<0x4E>(bv), dpp_i<0x4E>(bj));
      ARGMIN_COMBINE(dpp_f<0x141>(bv), dpp_i<0x141>(bj));
      ARGMIN_COMBINE(dpp_f<0x140>(bv), dpp_i<0x140>(bj));
      ARGMIN_COMBINE(__shfl_xor(bv, 16, 64), __shfl_xor(bj, 16, 64));
      ARGMIN_COMBINE(__shfl_xor(bv, 32, 64), __shfl_xor(bj, 32, 64));
      sel[s] = bj;
#pragma unroll
      for (int c = 0; c < 8; ++c)
        if (c * 64 + lane == bj) dv[c] = FLT_MAX;
    }
  }

  // --- gathers (scalar base via readfirstlane; all issued together) ---
  float4 ej[K][3];
  int valid[K];
#pragma unroll
  for (int s = 0; s < K; ++s) {
    int js = __builtin_amdgcn_readfirstlane(sel[s]);   // wave-uniform
    const float4* ero = e4 + (size_t)(b * NN + js) * H4;
#pragma unroll
    for (int q = 0; q < 3; ++q) ej[s][q] = ero[q * 64 + lane];
    valid[s] = (!GUARD || s < k) ? mask[b * NN + js] : 0;
  }
  float4 Sv[3];
#pragma unroll
  for (int q = 0; q < 3; ++q) Sv[q] = S4[b * H4 + q * 64 + lane];

  // --- dot products (K-way ILP, DPP-assisted wave sum) ---
  float d[K];
#pragma unroll
  for (int s = 0; s < K; ++s) {
    float p = 0.f;
#pragma unroll
    for (int q = 0; q < 3; ++q) {
      p = fmaf(ei[q].x, ej[s][q].x, p);
      p = fmaf(ei[q].y, ej[s][q].y, p);
      p = fmaf(ei[q].z, ej[s][q].z, p);
      p = fmaf(ei[q].w, ej[s][q].w, p);
    }
    d[s] = wave_sum64(p);
  }

  // --- sparse softmax closed form ---
  float M = 0.f;
  int m = 0;
#pragma unroll
  for (int s = 0; s < K; ++s)
    if (valid[s]) { ++m; M = fmaxf(M, d[s]); }
  float e0 = expf(-M);
  float Z = (float)(NN - m) * e0;
  float es[K];
#pragma unroll
  for (int s = 0; s < K; ++s) {
    es[s] = valid[s] ? expf(d[s] - M) : 0.f;
    Z += es[s];
  }
  float invZ = 1.0f / Z;
  float c0 = e0 * invZ;

  // --- context accumulation ---
  float4 ctx[3];
#pragma unroll
  for (int q = 0; q < 3; ++q) {
    ctx[q].x = c0 * Sv[q].x; ctx[q].y = c0 * Sv[q].y;
    ctx[q].z = c0 * Sv[q].z; ctx[q].w = c0 * Sv[q].w;
  }
#pragma unroll
  for (int s = 0; s < K; ++s) {
    if (valid[s]) {                            // wave-uniform
      float cs = es[s] * invZ - c0;
#pragma unroll
      for (int q = 0; q < 3; ++q) {
        ctx[q].x = fmaf(cs, ej[s][q].x, ctx[q].x);
        ctx[q].y = fmaf(cs, ej[s][q].y, ctx[q].y);
        ctx[q].z = fmaf(cs, ej[s][q].z, ctx[q].z);
        ctx[q].w = fmaf(cs, ej[s][q].w, ctx[q].w);
      }
    }
  }

  // --- store [e_i | ctx] ---
  size_t ob = (size_t)row * (2 * H4);
#pragma unroll
  for (int q = 0; q < 3; ++q) nt_store4(out4 + ob + q * 64 + lane, ei[q]);
#pragma unroll
  for (int q = 0; q < 3; ++q) nt_store4(out4 + ob + H4 + q * 64 + lane, ctx[q]);
}

// ---------------------------------------------------------------------------
// Kernel 3: one wave per output row; chunked XCD swizzle (4096 blocks, 8 XCDs).
// ---------------------------------------------------------------------------
__global__ __launch_bounds__(256) void fuse_kernel(const float2* __restrict__ ctr,
                                                   const float4* __restrict__ e4,
                                                   const int* __restrict__ mask,
                                                   const float4* __restrict__ S4,
                                                   const int* __restrict__ kptr,
                                                   float4* __restrict__ out4) {
  int bid = blockIdx.x;
  int swz = (bid & 7) * (ROWS / 4 / 8) + (bid >> 3);  // bijective: 4096 % 8 == 0
  int wid = threadIdx.x >> 6;
  int lane = threadIdx.x & 63;
  int row = swz * 4 + wid;
  int b = row >> 9;
  int i = row & (NN - 1);
  int k = *kptr;
  if (k == 5) {
    fuse_body<5, false>(ctr, mask, S4, e4, out4, row, b, i, lane, 5);
  } else {
    if (k > MAXK) k = MAXK;
    if (k < 0) k = 0;
    fuse_body<MAXK, true>(ctr, mask, S4, e4, out4, row, b, i, lane, k);
  }
}

// ---------------------------------------------------------------------------
extern "C" void kernel_launch(void* const* d_in, const int* in_sizes, int n_in,
                              void* d_out, int out_size, void* d_ws, size_t ws_size,
                              hipStream_t stream) {
  const float* encI = (const float*)d_in[0];
  const int* RoI_mask = (const int*)d_in[1];
  const float* spatials = (const float*)d_in[2];
  const int* kptr = (const int*)d_in[3];

  const size_t ctr_bytes = (size_t)ROWS * sizeof(float2);              // 128 KB
  const size_t s4_bytes = (size_t)NB * H4 * sizeof(float4);            // 96 KB
  const size_t part_bytes = (size_t)NB * CHUNKS * H4 * sizeof(float4); // 3 MB

  float2* ctr = (float2*)d_ws;
  float4* S4 = (float4*)((char*)d_ws + ctr_bytes);
  float4* part;
  if (ws_size >= ctr_bytes + s4_bytes + part_bytes) {
    part = (float4*)((char*)d_ws + ctr_bytes + s4_bytes);              // in ws
  } else {
    part = (float4*)d_out;  // front of d_out; consumed by reduce before fuse writes
  }

  prep_kernel<<<832, 256, 0, stream>>>(spatials, RoI_mask, (const float4*)encI, ctr, part);
  rowsum_reduce_kernel<<<24, 256, 0, stream>>>(part, S4);
  fuse_kernel<<<ROWS / 4, 256, 0, stream>>>(ctr, (const float4*)encI, RoI_mask, S4, kptr,
                                            (float4*)d_out);
  (void)in_sizes; (void)n_in; (void)out_size;
}

// Round 7
// 47.194 us; speedup vs baseline: 1.4599x; 1.0528x over previous
//
#include <hip/hip_runtime.h>
#include <cfloat>
#include <cstddef>

// Problem constants (fixed by setup_inputs): B=32, n=512, H=768, k=5
#define NB 32
#define NN 512
#define NH 768
#define H4 (NH / 4)        // 192 float4 per encI row
#define ROWS (NB * NN)     // 16384
#define MAXK 8
#define CHUNKS 32          // row-sum partial chunks per batch
#define RPC (NN / CHUNKS)  // 16 rows per chunk
#define INF_C 3000.0f
#define SELF_D 9000000.0f  // INF*INF self-distance

typedef float f32x4 __attribute__((ext_vector_type(4)));

__device__ __forceinline__ void nt_store4(float4* p, float4 v) {
  f32x4 t; t.x = v.x; t.y = v.y; t.z = v.z; t.w = v.w;
  __builtin_nontemporal_store(t, (f32x4*)p);
}

// ---------------------------------------------------------------------------
// DPP cross-lane moves (VALU pipe). Ctrl codes validated in rounds 4/6:
//   0xB1 = quad_perm xor1, 0x4E = quad_perm xor2,
//   0x141 = row_half_mirror (xor7), 0x140 = row_mirror (xor15).
// After the 4 steps every 16-lane group holds the group-wide combine;
// lanes 0/16/32/48 are then read with v_readlane and combined scalar-side.
// ---------------------------------------------------------------------------
template <int CTRL>
__device__ __forceinline__ int dpp_i(int x) {
  return __builtin_amdgcn_update_dpp(0, x, CTRL, 0xF, 0xF, true);
}
template <int CTRL>
__device__ __forceinline__ float dpp_f(float x) {
  return __int_as_float(dpp_i<CTRL>(__float_as_int(x)));
}

// 64-lane sum: 4 DPP adds -> per-16-group sums, then readlane 0/16/32/48 and
// 3 uniform VALU adds. No LDS-pipe (ds_swizzle/ds_bpermute) ops at all.
__device__ __forceinline__ float wave_sum64(float x) {
  x += dpp_f<0xB1>(x);
  x += dpp_f<0x4E>(x);
  x += dpp_f<0x141>(x);
  x += dpp_f<0x140>(x);
  int xi = __float_as_int(x);
  float a = __int_as_float(__builtin_amdgcn_readlane(xi, 0));
  float b = __int_as_float(__builtin_amdgcn_readlane(xi, 16));
  float c = __int_as_float(__builtin_amdgcn_readlane(xi, 32));
  float d = __int_as_float(__builtin_amdgcn_readlane(xi, 48));
  return (a + b) + (c + d);
}

// lexicographic argmin step on (bv,bj): (bv,bj) <- min((bv,bj),(ov,oj))
#define ARGMIN_COMBINE(ov, oj)                                       \
  do {                                                               \
    float _ov = (ov); int _oj = (oj);                                \
    if (_ov < bv || (_ov == bv && _oj < bj)) { bv = _ov; bj = _oj; } \
  } while (0)

// ---------------------------------------------------------------------------
// Kernel 1: blocks [0,768): row-sum partials (32 chunks x 16 rows per batch)
//           blocks [768,832): adjusted box centers
// ---------------------------------------------------------------------------
__global__ __launch_bounds__(256) void prep_kernel(const float* __restrict__ sp,
                                                   const int* __restrict__ mask,
                                                   const float4* __restrict__ e4,
                                                   float2* __restrict__ ctr,
                                                   float4* __restrict__ part) {
  int bid = blockIdx.x;
  if (bid < 768) {
    int t = bid * 256 + threadIdx.x;          // [0, NB*CHUNKS*H4)
    int h4 = t % H4;
    int bc = t / H4;
    int b = bc >> 5, chunk = bc & 31;
    const float4* p = e4 + ((size_t)(b * NN + chunk * RPC)) * H4 + h4;
    float ax = 0.f, ay = 0.f, az = 0.f, aw = 0.f;
#pragma unroll
    for (int r = 0; r < RPC; ++r) {
      float4 v = p[(size_t)r * H4];
      ax += v.x; ay += v.y; az += v.z; aw += v.w;
    }
    part[t] = make_float4(ax, ay, az, aw);
  } else {
    int t = (bid - 768) * 256 + threadIdx.x;  // [0, ROWS)
    const float* s = sp + (size_t)t * 6;
    float cx = __fmul_rn(__fadd_rn(s[0], s[2]), 0.5f);
    float cy = __fmul_rn(__fadd_rn(s[1], s[3]), 0.5f);
    if (mask[t] == 0) { cx = __fadd_rn(cx, INF_C); cy = __fadd_rn(cy, INF_C); }
    ctr[t] = make_float2(cx, cy);
  }
}

// ---------------------------------------------------------------------------
// Kernel 2: reduce 32 chunk-partials -> S[b][h4]  (24 blocks, ~1-2 us)
// ---------------------------------------------------------------------------
__global__ __launch_bounds__(256) void rowsum_reduce_kernel(const float4* __restrict__ part,
                                                            float4* __restrict__ S4) {
  int t = blockIdx.x * 256 + threadIdx.x;     // [0, NB*H4)
  int h4 = t % H4;
  int b = t / H4;
  float ax = 0.f, ay = 0.f, az = 0.f, aw = 0.f;
#pragma unroll
  for (int c = 0; c < CHUNKS; ++c) {
    float4 v = part[(size_t)(b * CHUNKS + c) * H4 + h4];
    ax += v.x; ay += v.y; az += v.z; aw += v.w;
  }
  S4[t] = make_float4(ax, ay, az, aw);
}

// ---------------------------------------------------------------------------
// Fused body: topk (DPP + readlane-scalar argmin, gathers issued per-round) +
// dots + sparse softmax + context.
// context = c0*S + sum_valid (c_s - c0) * e_j,
//   c_s = exp(sim_s - M)/Z, c0 = exp(-M)/Z,
//   Z = (512 - m)*exp(-M) + sum_valid exp(sim_s - M), M = max(0, max valid sim)
// GUARD=false requires k == K exactly.
// ---------------------------------------------------------------------------
template <int K, bool GUARD>
__device__ __forceinline__ void fuse_body(const float2* __restrict__ ctr,
                                          const int* __restrict__ mask,
                                          const float4* __restrict__ S4,
                                          const float4* __restrict__ e4,
                                          float4* __restrict__ out4,
                                          int row, int b, int i, int lane, int k) {
  // issue own-row + batch-sum loads FIRST; latency hides under topk compute
  const float4* erow = e4 + (size_t)row * H4;
  float4 ei[3];
#pragma unroll
  for (int q = 0; q < 3; ++q) ei[q] = erow[q * 64 + lane];
  float4 Sv[3];
#pragma unroll
  for (int q = 0; q < 3; ++q) Sv[q] = S4[b * H4 + q * 64 + lane];

  // --- distances (8 candidates per lane) ---
  float2 ci = ctr[b * NN + i];
  float dv[8];
#pragma unroll
  for (int c = 0; c < 8; ++c) {
    int j = c * 64 + lane;
    float2 cj = ctr[b * NN + j];
    float dx = __fadd_rn(ci.x, -cj.x);
    float dy = __fadd_rn(ci.y, -cj.y);
    float d = __fsqrt_rn(__fadd_rn(__fmul_rn(dx, dx), __fmul_rn(dy, dy)));
    dv[c] = (j == i) ? SELF_D : d;
  }

  // --- top-k extraction; gather for winner s issued inside round s ---
  int sel[K];
  int valid[K];
  float4 ej[K][3];
#pragma unroll
  for (int s = 0; s < K; ++s) {
    sel[s] = 0;
    valid[s] = 0;
    if (!GUARD || s < k) {                    // wave-uniform
      // local lexicographic min over this lane's 8 candidates
      float bv = FLT_MAX;
      int bj = 1 << 30;
#pragma unroll
      for (int c = 0; c < 8; ++c) {
        int j = c * 64 + lane;
        if (dv[c] < bv) { bv = dv[c]; bj = j; }
      }
      // 4 DPP steps -> per-16-lane-group argmin (xor-generators {1,2,7,15})
      ARGMIN_COMBINE(dpp_f<0xB1>(bv), dpp_i<0xB1>(bj));
      ARGMIN_COMBINE(dpp_f<0x4E>(bv), dpp_i<0x4E>(bj));
      ARGMIN_COMBINE(dpp_f<0x141>(bv), dpp_i<0x141>(bj));
      ARGMIN_COMBINE(dpp_f<0x140>(bv), dpp_i<0x140>(bj));
      // readlane 0/16/32/48 + scalar u64 lexicographic min.
      // dist >= 0 -> f32 bits are order-preserving as unsigned;
      // key = (dist_bits<<32)|j gives (dist asc, j asc) = jax.lax.top_k order.
      int bvi = __float_as_int(bv);
      unsigned long long k0 =
          ((unsigned long long)(unsigned)__builtin_amdgcn_readlane(bvi, 0) << 32) |
          (unsigned)__builtin_amdgcn_readlane(bj, 0);
      unsigned long long k1 =
          ((unsigned long long)(unsigned)__builtin_amdgcn_readlane(bvi, 16) << 32) |
          (unsigned)__builtin_amdgcn_readlane(bj, 16);
      unsigned long long k2 =
          ((unsigned long long)(unsigned)__builtin_amdgcn_readlane(bvi, 32) << 32) |
          (unsigned)__builtin_amdgcn_readlane(bj, 32);
      unsigned long long k3 =
          ((unsigned long long)(unsigned)__builtin_amdgcn_readlane(bvi, 48) << 32) |
          (unsigned)__builtin_amdgcn_readlane(bj, 48);
      unsigned long long kb = k0 < k1 ? k0 : k1;
      unsigned long long kc = k2 < k3 ? k2 : k3;
      kb = kb < kc ? kb : kc;
      int js = (int)(unsigned)kb;             // uniform (SGPR) winner index
      sel[s] = js;
      // remove winner from its owner lane
#pragma unroll
      for (int c = 0; c < 8; ++c)
        if (c * 64 + lane == js) dv[c] = FLT_MAX;
      // issue this winner's gather + mask NOW (overlaps remaining rounds)
      const float4* ero = e4 + (size_t)(b * NN + js) * H4;
#pragma unroll
      for (int q = 0; q < 3; ++q) ej[s][q] = ero[q * 64 + lane];
      valid[s] = mask[b * NN + js];
    }
  }

  // --- dot products (K-way ILP, DPP+readlane wave sum) ---
  float d[K];
#pragma unroll
  for (int s = 0; s < K; ++s) {
    float p = 0.f;
#pragma unroll
    for (int q = 0; q < 3; ++q) {
      p = fmaf(ei[q].x, ej[s][q].x, p);
      p = fmaf(ei[q].y, ej[s][q].y, p);
      p = fmaf(ei[q].z, ej[s][q].z, p);
      p = fmaf(ei[q].w, ej[s][q].w, p);
    }
    d[s] = wave_sum64(p);
  }

  // --- sparse softmax closed form ---
  float M = 0.f;
  int m = 0;
#pragma unroll
  for (int s = 0; s < K; ++s)
    if (valid[s]) { ++m; M = fmaxf(M, d[s]); }
  float e0 = expf(-M);
  float Z = (float)(NN - m) * e0;
  float es[K];
#pragma unroll
  for (int s = 0; s < K; ++s) {
    es[s] = valid[s] ? expf(d[s] - M) : 0.f;
    Z += es[s];
  }
  float invZ = 1.0f / Z;
  float c0 = e0 * invZ;

  // --- context accumulation ---
  float4 ctx[3];
#pragma unroll
  for (int q = 0; q < 3; ++q) {
    ctx[q].x = c0 * Sv[q].x; ctx[q].y = c0 * Sv[q].y;
    ctx[q].z = c0 * Sv[q].z; ctx[q].w = c0 * Sv[q].w;
  }
#pragma unroll
  for (int s = 0; s < K; ++s) {
    if (valid[s]) {                            // wave-uniform
      float cs = es[s] * invZ - c0;
#pragma unroll
      for (int q = 0; q < 3; ++q) {
        ctx[q].x = fmaf(cs, ej[s][q].x, ctx[q].x);
        ctx[q].y = fmaf(cs, ej[s][q].y, ctx[q].y);
        ctx[q].z = fmaf(cs, ej[s][q].z, ctx[q].z);
        ctx[q].w = fmaf(cs, ej[s][q].w, ctx[q].w);
      }
    }
  }

  // --- store [e_i | ctx] ---
  size_t ob = (size_t)row * (2 * H4);
#pragma unroll
  for (int q = 0; q < 3; ++q) nt_store4(out4 + ob + q * 64 + lane, ei[q]);
#pragma unroll
  for (int q = 0; q < 3; ++q) nt_store4(out4 + ob + H4 + q * 64 + lane, ctx[q]);
}

// ---------------------------------------------------------------------------
// Kernel 3: one wave per output row; chunked XCD swizzle (4096 blocks, 8 XCDs).
// ---------------------------------------------------------------------------
__global__ __launch_bounds__(256) void fuse_kernel(const float2* __restrict__ ctr,
                                                   const float4* __restrict__ e4,
                                                   const int* __restrict__ mask,
                                                   const float4* __restrict__ S4,
                                                   const int* __restrict__ kptr,
                                                   float4* __restrict__ out4) {
  int bid = blockIdx.x;
  int swz = (bid & 7) * (ROWS / 4 / 8) + (bid >> 3);  // bijective: 4096 % 8 == 0
  int wid = threadIdx.x >> 6;
  int lane = threadIdx.x & 63;
  int row = swz * 4 + wid;
  int b = row >> 9;
  int i = row & (NN - 1);
  int k = *kptr;
  if (k == 5) {
    fuse_body<5, false>(ctr, mask, S4, e4, out4, row, b, i, lane, 5);
  } else {
    if (k > MAXK) k = MAXK;
    if (k < 0) k = 0;
    fuse_body<MAXK, true>(ctr, mask, S4, e4, out4, row, b, i, lane, k);
  }
}

// ---------------------------------------------------------------------------
extern "C" void kernel_launch(void* const* d_in, const int* in_sizes, int n_in,
                              void* d_out, int out_size, void* d_ws, size_t ws_size,
                              hipStream_t stream) {
  const float* encI = (const float*)d_in[0];
  const int* RoI_mask = (const int*)d_in[1];
  const float* spatials = (const float*)d_in[2];
  const int* kptr = (const int*)d_in[3];

  const size_t ctr_bytes = (size_t)ROWS * sizeof(float2);              // 128 KB
  const size_t s4_bytes = (size_t)NB * H4 * sizeof(float4);            // 96 KB
  const size_t part_bytes = (size_t)NB * CHUNKS * H4 * sizeof(float4); // 3 MB

  float2* ctr = (float2*)d_ws;
  float4* S4 = (float4*)((char*)d_ws + ctr_bytes);
  float4* part;
  if (ws_size >= ctr_bytes + s4_bytes + part_bytes) {
    part = (float4*)((char*)d_ws + ctr_bytes + s4_bytes);              // in ws
  } else {
    part = (float4*)d_out;  // front of d_out; consumed by reduce before fuse writes
  }

  prep_kernel<<<832, 256, 0, stream>>>(spatials, RoI_mask, (const float4*)encI, ctr, part);
  rowsum_reduce_kernel<<<24, 256, 0, stream>>>(part, S4);
  fuse_kernel<<<ROWS / 4, 256, 0, stream>>>(ctr, (const float4*)encI, RoI_mask, S4, kptr,
                                            (float4*)d_out);
  (void)in_sizes; (void)n_in; (void)out_size;
}

// Round 9
// 44.637 us; speedup vs baseline: 1.5435x; 1.0573x over previous
//
#include <hip/hip_runtime.h>
#include <cfloat>
#include <cstddef>

// Problem constants (fixed by setup_inputs): B=32, n=512, H=768, k=5
#define NB 32
#define NN 512
#define NH 768
#define H4 (NH / 4)        // 192 float4 per encI row
#define ROWS (NB * NN)     // 16384
#define MAXK 8
#define CHUNKS 32          // row-sum partial chunks per batch
#define RPC (NN / CHUNKS)  // 16 rows per chunk
#define INF_C 3000.0f
#define SELF_D 9000000.0f  // INF*INF self-distance

typedef float f32x4 __attribute__((ext_vector_type(4)));

__device__ __forceinline__ void nt_store4(float4* p, float4 v) {
  f32x4 t; t.x = v.x; t.y = v.y; t.z = v.z; t.w = v.w;
  __builtin_nontemporal_store(t, (f32x4*)p);
}

// ---------------------------------------------------------------------------
// DPP cross-lane moves (VALU pipe). Ctrl codes validated rounds 4/6/7:
//   0xB1 = quad_perm xor1, 0x4E = quad_perm xor2,
//   0x141 = row_half_mirror (xor7), 0x140 = row_mirror (xor15).
// ---------------------------------------------------------------------------
template <int CTRL>
__device__ __forceinline__ int dpp_i(int x) {
  return __builtin_amdgcn_update_dpp(0, x, CTRL, 0xF, 0xF, true);
}
template <int CTRL>
__device__ __forceinline__ float dpp_f(float x) {
  return __int_as_float(dpp_i<CTRL>(__float_as_int(x)));
}

// 64-lane sum: 4 DPP adds -> per-16-group sums, then readlane 0/16/32/48.
__device__ __forceinline__ float wave_sum64(float x) {
  x += dpp_f<0xB1>(x);
  x += dpp_f<0x4E>(x);
  x += dpp_f<0x141>(x);
  x += dpp_f<0x140>(x);
  int xi = __float_as_int(x);
  float a = __int_as_float(__builtin_amdgcn_readlane(xi, 0));
  float b = __int_as_float(__builtin_amdgcn_readlane(xi, 16));
  float c = __int_as_float(__builtin_amdgcn_readlane(xi, 32));
  float d = __int_as_float(__builtin_amdgcn_readlane(xi, 48));
  return (a + b) + (c + d);
}

// lexicographic argmin step on (bv,bj): (bv,bj) <- min((bv,bj),(ov,oj))
#define ARGMIN_COMBINE(ov, oj)                                       \
  do {                                                               \
    float _ov = (ov); int _oj = (oj);                                \
    if (_ov < bv || (_ov == bv && _oj < bj)) { bv = _ov; bj = _oj; } \
  } while (0)

// ---------------------------------------------------------------------------
// Kernel 1: blocks [0,768): row-sum partials (32 chunks x 16 rows per batch)
//           blocks [768,832): adjusted box centers
// ---------------------------------------------------------------------------
__global__ __launch_bounds__(256) void prep_kernel(const float* __restrict__ sp,
                                                   const int* __restrict__ mask,
                                                   const float4* __restrict__ e4,
                                                   float2* __restrict__ ctr,
                                                   float4* __restrict__ part) {
  int bid = blockIdx.x;
  if (bid < 768) {
    int t = bid * 256 + threadIdx.x;          // [0, NB*CHUNKS*H4)
    int h4 = t % H4;
    int bc = t / H4;
    int b = bc >> 5, chunk = bc & 31;
    const float4* p = e4 + ((size_t)(b * NN + chunk * RPC)) * H4 + h4;
    float ax = 0.f, ay = 0.f, az = 0.f, aw = 0.f;
#pragma unroll
    for (int r = 0; r < RPC; ++r) {
      float4 v = p[(size_t)r * H4];
      ax += v.x; ay += v.y; az += v.z; aw += v.w;
    }
    part[t] = make_float4(ax, ay, az, aw);
  } else {
    int t = (bid - 768) * 256 + threadIdx.x;  // [0, ROWS)
    const float* s = sp + (size_t)t * 6;
    float cx = __fmul_rn(__fadd_rn(s[0], s[2]), 0.5f);
    float cy = __fmul_rn(__fadd_rn(s[1], s[3]), 0.5f);
    if (mask[t] == 0) { cx = __fadd_rn(cx, INF_C); cy = __fadd_rn(cy, INF_C); }
    ctr[t] = make_float2(cx, cy);
  }
}

// ---------------------------------------------------------------------------
// Kernel 2: reduce 32 chunk-partials -> S[b][h4]  (24 blocks, ~1-2 us)
// ---------------------------------------------------------------------------
__global__ __launch_bounds__(256) void rowsum_reduce_kernel(const float4* __restrict__ part,
                                                            float4* __restrict__ S4) {
  int t = blockIdx.x * 256 + threadIdx.x;     // [0, NB*H4)
  int h4 = t % H4;
  int b = t / H4;
  float ax = 0.f, ay = 0.f, az = 0.f, aw = 0.f;
#pragma unroll
  for (int c = 0; c < CHUNKS; ++c) {
    float4 v = part[(size_t)(b * CHUNKS + c) * H4 + h4];
    ax += v.x; ay += v.y; az += v.z; aw += v.w;
  }
  S4[t] = make_float4(ax, ay, az, aw);
}

// ---------------------------------------------------------------------------
// Fused body, register-lean online form.
// Weights: selected&valid j get exp(sim_j - M)/Z, all others exp(-M)/Z, with
// M = max(0, max valid sim), Z = (512-m)e^{-M} + sum es. Online accumulation:
//   ctxA = sum_s (es_s - e0) * e_j, rescaled by exp(M_old-M_new) on max growth
//   ctx  = invZ * (e0 * S + ctxA)
// Each term telescopes to exp(ds_s - M_fin) - exp(-M_fin): identical weights
// to rounds 2-7's closed form; only fp rounding differs.
// GUARD=false requires k == K exactly.
// ---------------------------------------------------------------------------
template <int K, bool GUARD>
__device__ __forceinline__ void fuse_body(const float2* __restrict__ ctr,
                                          const int* __restrict__ mask,
                                          const float4* __restrict__ S4,
                                          const float4* __restrict__ e4,
                                          float4* __restrict__ out4,
                                          int row, int b, int i, int lane, int k) {
  // issue own-row loads FIRST; latency hides under distance/topk compute
  const float4* erow = e4 + (size_t)row * H4;
  float4 ei[3];
#pragma unroll
  for (int q = 0; q < 3; ++q) ei[q] = erow[q * 64 + lane];

  // --- distances (8 candidates per lane) ---
  float2 ci = ctr[b * NN + i];
  float dv[8];
#pragma unroll
  for (int c = 0; c < 8; ++c) {
    int j = c * 64 + lane;
    float2 cj = ctr[b * NN + j];
    float dx = __fadd_rn(ci.x, -cj.x);
    float dy = __fadd_rn(ci.y, -cj.y);
    float d = __fsqrt_rn(__fadd_rn(__fmul_rn(dx, dx), __fmul_rn(dy, dy)));
    dv[c] = (j == i) ? SELF_D : d;
  }

  // --- phase 1: top-k extraction only (dv live; no gathers yet) ---
  // ties -> smaller index == jax.lax.top_k order (key = dist_bits<<32 | j)
  int sel[K];
#pragma unroll
  for (int s = 0; s < K; ++s) {
    sel[s] = 0;
    if (!GUARD || s < k) {                    // wave-uniform
      float bv = FLT_MAX;
      int bj = 1 << 30;
#pragma unroll
      for (int c = 0; c < 8; ++c) {
        int j = c * 64 + lane;
        if (dv[c] < bv) { bv = dv[c]; bj = j; }
      }
      ARGMIN_COMBINE(dpp_f<0xB1>(bv), dpp_i<0xB1>(bj));
      ARGMIN_COMBINE(dpp_f<0x4E>(bv), dpp_i<0x4E>(bj));
      ARGMIN_COMBINE(dpp_f<0x141>(bv), dpp_i<0x141>(bj));
      ARGMIN_COMBINE(dpp_f<0x140>(bv), dpp_i<0x140>(bj));
      int bvi = __float_as_int(bv);
      unsigned long long k0 =
          ((unsigned long long)(unsigned)__builtin_amdgcn_readlane(bvi, 0) << 32) |
          (unsigned)__builtin_amdgcn_readlane(bj, 0);
      unsigned long long k1 =
          ((unsigned long long)(unsigned)__builtin_amdgcn_readlane(bvi, 16) << 32) |
          (unsigned)__builtin_amdgcn_readlane(bj, 16);
      unsigned long long k2 =
          ((unsigned long long)(unsigned)__builtin_amdgcn_readlane(bvi, 32) << 32) |
          (unsigned)__builtin_amdgcn_readlane(bj, 32);
      unsigned long long k3 =
          ((unsigned long long)(unsigned)__builtin_amdgcn_readlane(bvi, 48) << 32) |
          (unsigned)__builtin_amdgcn_readlane(bj, 48);
      unsigned long long kb = k0 < k1 ? k0 : k1;
      unsigned long long kc = k2 < k3 ? k2 : k3;
      kb = kb < kc ? kb : kc;
      int js = (int)(unsigned)kb;             // uniform (SGPR) winner index
      sel[s] = js;
#pragma unroll
      for (int c = 0; c < 8; ++c)
        if (c * 64 + lane == js) dv[c] = FLT_MAX;
    }
  }

  // --- phase 2: single gather pass with online softmax-context ---
  float M = 0.f, e0 = 1.f, sumE = 0.f;
  int m = 0;
  float4 ctxA[3];
#pragma unroll
  for (int q = 0; q < 3; ++q) ctxA[q] = make_float4(0.f, 0.f, 0.f, 0.f);

#pragma unroll
  for (int s = 0; s < K; ++s) {
    if (!GUARD || s < k) {                    // wave-uniform
      int js = sel[s];
      int vld = mask[b * NN + js];            // uniform-addr load
      const float4* ero = e4 + (size_t)(b * NN + js) * H4;
      float4 ej0 = ero[0 * 64 + lane];
      float4 ej1 = ero[1 * 64 + lane];
      float4 ej2 = ero[2 * 64 + lane];
      float p = 0.f;
      p = fmaf(ei[0].x, ej0.x, p); p = fmaf(ei[0].y, ej0.y, p);
      p = fmaf(ei[0].z, ej0.z, p); p = fmaf(ei[0].w, ej0.w, p);
      p = fmaf(ei[1].x, ej1.x, p); p = fmaf(ei[1].y, ej1.y, p);
      p = fmaf(ei[1].z, ej1.z, p); p = fmaf(ei[1].w, ej1.w, p);
      p = fmaf(ei[2].x, ej2.x, p); p = fmaf(ei[2].y, ej2.y, p);
      p = fmaf(ei[2].z, ej2.z, p); p = fmaf(ei[2].w, ej2.w, p);
      float ds = wave_sum64(p);
      if (vld) {                              // wave-uniform
        ++m;
        float nm = fmaxf(M, ds);
        float scale = expf(M - nm);           // 1.0 when max unchanged
        float es = expf(ds - nm);
        M = nm;                               // <-- the round-8 bug: was missing
        e0 = expf(-nm);
        sumE = fmaf(sumE, scale, es);
        float w = es - e0;
        ctxA[0].x = fmaf(ctxA[0].x, scale, w * ej0.x);
        ctxA[0].y = fmaf(ctxA[0].y, scale, w * ej0.y);
        ctxA[0].z = fmaf(ctxA[0].z, scale, w * ej0.z);
        ctxA[0].w = fmaf(ctxA[0].w, scale, w * ej0.w);
        ctxA[1].x = fmaf(ctxA[1].x, scale, w * ej1.x);
        ctxA[1].y = fmaf(ctxA[1].y, scale, w * ej1.y);
        ctxA[1].z = fmaf(ctxA[1].z, scale, w * ej1.z);
        ctxA[1].w = fmaf(ctxA[1].w, scale, w * ej1.w);
        ctxA[2].x = fmaf(ctxA[2].x, scale, w * ej2.x);
        ctxA[2].y = fmaf(ctxA[2].y, scale, w * ej2.y);
        ctxA[2].z = fmaf(ctxA[2].z, scale, w * ej2.z);
        ctxA[2].w = fmaf(ctxA[2].w, scale, w * ej2.w);
      }
    }
  }

  // --- phase 3: finalize (Sv loaded only now) + stores ---
  float Z = fmaf((float)(NN - m), e0, sumE);
  float invZ = 1.0f / Z;
  size_t ob = (size_t)row * (2 * H4);
#pragma unroll
  for (int q = 0; q < 3; ++q) nt_store4(out4 + ob + q * 64 + lane, ei[q]);
#pragma unroll
  for (int q = 0; q < 3; ++q) {
    float4 Sv = S4[b * H4 + q * 64 + lane];
    float4 cx;
    cx.x = invZ * fmaf(e0, Sv.x, ctxA[q].x);
    cx.y = invZ * fmaf(e0, Sv.y, ctxA[q].y);
    cx.z = invZ * fmaf(e0, Sv.z, ctxA[q].z);
    cx.w = invZ * fmaf(e0, Sv.w, ctxA[q].w);
    nt_store4(out4 + ob + H4 + q * 64 + lane, cx);
  }
}

// ---------------------------------------------------------------------------
// Kernel 3: one wave per output row; chunked XCD swizzle (4096 blocks, 8 XCDs).
// __launch_bounds__(256, 8): force <=64 VGPR tier -> 8 waves/SIMD.
// ---------------------------------------------------------------------------
__global__ __launch_bounds__(256, 8) void fuse_kernel(const float2* __restrict__ ctr,
                                                      const float4* __restrict__ e4,
                                                      const int* __restrict__ mask,
                                                      const float4* __restrict__ S4,
                                                      const int* __restrict__ kptr,
                                                      float4* __restrict__ out4) {
  int bid = blockIdx.x;
  int swz = (bid & 7) * (ROWS / 4 / 8) + (bid >> 3);  // bijective: 4096 % 8 == 0
  int wid = threadIdx.x >> 6;
  int lane = threadIdx.x & 63;
  int row = swz * 4 + wid;
  int b = row >> 9;
  int i = row & (NN - 1);
  int k = *kptr;
  if (k == 5) {
    fuse_body<5, false>(ctr, mask, S4, e4, out4, row, b, i, lane, 5);
  } else {
    if (k > MAXK) k = MAXK;
    if (k < 0) k = 0;
    fuse_body<MAXK, true>(ctr, mask, S4, e4, out4, row, b, i, lane, k);
  }
}

// ---------------------------------------------------------------------------
extern "C" void kernel_launch(void* const* d_in, const int* in_sizes, int n_in,
                              void* d_out, int out_size, void* d_ws, size_t ws_size,
                              hipStream_t stream) {
  const float* encI = (const float*)d_in[0];
  const int* RoI_mask = (const int*)d_in[1];
  const float* spatials = (const float*)d_in[2];
  const int* kptr = (const int*)d_in[3];

  const size_t ctr_bytes = (size_t)ROWS * sizeof(float2);              // 128 KB
  const size_t s4_bytes = (size_t)NB * H4 * sizeof(float4);            // 96 KB
  const size_t part_bytes = (size_t)NB * CHUNKS * H4 * sizeof(float4); // 3 MB

  float2* ctr = (float2*)d_ws;
  float4* S4 = (float4*)((char*)d_ws + ctr_bytes);
  float4* part;
  if (ws_size >= ctr_bytes + s4_bytes + part_bytes) {
    part = (float4*)((char*)d_ws + ctr_bytes + s4_bytes);              // in ws
  } else {
    part = (float4*)d_out;  // front of d_out; consumed by reduce before fuse writes
  }

  prep_kernel<<<832, 256, 0, stream>>>(spatials, RoI_mask, (const float4*)encI, ctr, part);
  rowsum_reduce_kernel<<<24, 256, 0, stream>>>(part, S4);
  fuse_kernel<<<ROWS / 4, 256, 0, stream>>>(ctr, (const float4*)encI, RoI_mask, S4, kptr,
                                            (float4*)d_out);
  (void)in_sizes; (void)n_in; (void)out_size;
}